// Round 12
// baseline (102.915 us; speedup 1.0000x reference)
//
#include <hip/hip_runtime.h>
#include <hip/hip_bf16.h>

// Deformable conv2d (v1, align_corners=True, zeros padding), NHWC-bf16 + MFMA.
// R12 = R10/R11 tile structure, re-decomposed for 2x occupancy:
//  - 512-thread blocks (8 waves). Wave pair (g, g+4) shares a 16-pixel group;
//    wave g handles channels [0,32), wave g+4 handles [32,64). Per wave per
//    kn: 4 ds_read_b128 + 1 B-build + 4 MFMA (half of R11's per-wave work).
//  - __launch_bounds__(512,8): VGPR<=64 -> 4 blocks/CU = 32 waves/CU (100%
//    occupancy; every prior round ran <=16 waves/CU and waves were ~95%
//    stalled with only 3 other waves to cover -> the one untested lever).
//  - partial accs reduced via LDS (conflict-free [s][r][g][lane] layout,
//    aliasing the tile buffer after a barrier); cc=0 waves store.
// x(4,64,128,128) f32, offset(4,18,128,128) f32, weight(64,64,9) f32
// -> out(4,64,128,128) f32.  iy = oh + off_y, ix = ow + off_x.

#define NB 4
#define CI 64
#define HH 128
#define WW 128
#define OCH 64
#define KNN 9
#define HW (HH * WW)

typedef unsigned int u32;
typedef unsigned short u16;
typedef __attribute__((ext_vector_type(8))) short bf16x8;
typedef __attribute__((ext_vector_type(4))) float f32x4;

__device__ inline u16 f2bf(float f) {  // RNE
    u32 u = __float_as_uint(f);
    return (u16)((u + 0x7fffu + ((u >> 16) & 1u)) >> 16);
}
__device__ inline u32 pk2(float lo, float hi) {
    return (u32)f2bf(lo) | ((u32)f2bf(hi) << 16);
}
__device__ inline float2 up2v(u32 u) {
    return float2{__uint_as_float(u << 16), __uint_as_float(u & 0xffff0000u)};
}
__device__ inline u32 pkrn(float2 s) {
    union { __hip_bfloat162 b; u32 u; } c;
    c.b = __float22bfloat162_rn(s);
    return c.u;
}

// ---- prologue: x NCHW f32 -> NHWC bf16, + weight -> A-fragment order bf16.
// wf layout: frag[kn][chunk(2)][strip(4)][lane(64)][j(8)]; lane holds
// A[m=lane&15][k=(lane>>4)*8+j], oc = strip*16+m, c = chunk*32+k.
__global__ __launch_bounds__(256) void prep_kernel(const float* __restrict__ x,
                                                   const float* __restrict__ w,
                                                   u16* __restrict__ xT,
                                                   u16* __restrict__ wf) {
    __shared__ float T[64 * 68];
    const int tid = threadIdx.x;
    if (blockIdx.x < NB * 256) {
        const int n = blockIdx.x >> 8;
        const int hw0 = (blockIdx.x & 255) << 6;
#pragma unroll
        for (int jj = 0; jj < 4; jj++) {
            int c = (tid >> 4) + (jj << 4);
            int hwq = (tid & 15) << 2;
            float4 v = *(const float4*)&x[(((n << 6) + c) << 14) + hw0 + hwq];
            *(float4*)&T[c * 68 + hwq] = v;
        }
        __syncthreads();
        const int hw_l = tid >> 2;
        const int cb = (tid & 3) << 4;
        u32 ou[8];
#pragma unroll
        for (int k = 0; k < 8; k++) {
            ou[k] = pk2(T[(cb + 2 * k) * 68 + hw_l], T[(cb + 2 * k + 1) * 68 + hw_l]);
        }
        u16* dst = xT + ((size_t)((n << 14) + hw0 + hw_l) << 6) + cb;
        *(uint4*)dst = make_uint4(ou[0], ou[1], ou[2], ou[3]);
        *(uint4*)(dst + 8) = make_uint4(ou[4], ou[5], ou[6], ou[7]);
    } else {
        int i = (blockIdx.x - NB * 256) * 256 + tid;
        if (i < KNN * 2 * 4 * 64 * 8) {
            int j = i & 7, l = (i >> 3) & 63, strip = (i >> 9) & 3,
                chunk = (i >> 11) & 1, kn = i >> 12;
            int oc = strip * 16 + (l & 15);
            int c = chunk * 32 + ((l >> 4) & 3) * 8 + j;
            wf[i] = f2bf(w[(oc * CI + c) * KNN + kn]);
        }
    }
}

// ---- main kernel: 512 threads = 8 waves; wave (g, cc): pixel group g,
// channel half cc. LDS input tile as R10 (XOR-swizzled 16B chunks).
__global__ __launch_bounds__(512, 8) void dcn_main_kernel(const u16* __restrict__ xT,
                                                          const float* __restrict__ off,
                                                          const u16* __restrict__ wf,
                                                          float* __restrict__ out) {
    // 14x16 pixels x 64ch bf16; pixel row = 32 dw (128B); chunk q at q^(p&7).
    __shared__ __align__(16) u32 tile[224 * 32];  // 28,672 B (reused for reduce)
    const int tid = threadIdx.x;
    const int l = tid & 63;
    const int wv = tid >> 6;
    const int g = wv & 3;    // pixel group (4x4 quadrant of the 8x8 patch)
    const int cc = wv >> 2;  // channel half: 0 -> c[0,32), 1 -> c[32,64)

    // XCD-affine decode: xcd = blockIdx&7; n = xcd>>1; half = xcd&1.
    const int b = blockIdx.x;
    const int xcd = b & 7;
    const int n = xcd >> 1;
    const int patch = (b >> 3) + ((xcd & 1) << 7);  // 0..255
    const int py = ((patch >> 4) << 3), px = ((patch & 15) << 3);
    const int ty = min(max(py - 3, 0), HH - 14);
    const int tx = min(max(px - 4, 0), WW - 16);

    const u16* xTn = xT + ((size_t)n << 20);
    const float* offn = off + n * (2 * KNN * HW);

    // cooperative tile load: 1792 uint4; threads 0..447 move 4 each.
    if (tid < 448) {
        const int pp = tid >> 1;          // tile pixel 0..223
        const int hf = tid & 1;           // chunk half 0..1 (chunks 4h..4h+3)
        const int tr = pp >> 4, tc = pp & 15;
        const u16* src = xTn + ((((ty + tr) << 7) + (tx + tc)) << 6) + (hf << 5);
        u32* dst = &tile[pp << 5];
        const int sw = pp & 7;
#pragma unroll
        for (int j = 0; j < 4; j++) {
            const int q = (hf << 2) + j;
            *(uint4*)&dst[(q ^ sw) << 2] = *(const uint4*)(src + (j << 3));
        }
    }

    const int qy = ((g >> 1) << 2), qx = ((g & 1) << 2);
    const int col = l & 15;
    const int oh = py + qy + (col >> 2);
    const int ow = px + qx + (col & 3);
    const int rr = (oh << 7) + ow;
    const int qc = l >> 4;            // 16B sub-chunk within this wave's half
    const int q = (cc << 2) + qc;     // global 16B chunk index 0..7
    const int cbg = q << 3;           // global channel base (halfwords)

    const float* offp = offn + rr;
    float soy = offp[0];
    float sox = offp[HW];

    __syncthreads();  // tile resident

    const bf16x8* wfl = (const bf16x8*)wf + l;
    f32x4 acc[4] = {{0, 0, 0, 0}, {0, 0, 0, 0}, {0, 0, 0, 0}, {0, 0, 0, 0}};

#pragma unroll 3
    for (int kn = 0; kn < KNN; kn++) {
        float iy = (float)oh + soy, ix = (float)ow + sox;
        float y0f = floorf(iy), x0f = floorf(ix);
        float wy1 = iy - y0f, wy0 = 1.f - wy1;
        float wx1 = ix - x0f, wx0 = 1.f - wx1;
        float my0 = (y0f >= 0.f && y0f <= 127.f) ? 1.f : 0.f;
        float my1 = (y0f >= -1.f && y0f <= 126.f) ? 1.f : 0.f;
        float mx0 = (x0f >= 0.f && x0f <= 127.f) ? 1.f : 0.f;
        float mx1 = (x0f >= -1.f && x0f <= 126.f) ? 1.f : 0.f;
        float ax = wx0 * mx0, bx = wx1 * mx1;
        float cy = wy0 * my0, dy = wy1 * my1;
        int y0 = min(max((int)y0f, 0), 127), y1 = min(max((int)y0f + 1, 0), 127);
        int x0 = min(max((int)x0f, 0), 127), x1 = min(max((int)x0f + 1, 0), 127);

        const int dy0 = min(max(y0 - ty, 0), 13), dy1 = min(max(y1 - ty, 0), 13);
        const int dx0 = min(max(x0 - tx, 0), 15), dx1 = min(max(x1 - tx, 0), 15);
        const int P0 = (dy0 << 4) + dx0, P1 = (dy0 << 4) + dx1;
        const int P2 = (dy1 << 4) + dx0, P3 = (dy1 << 4) + dx1;
        const bool oot = (y0 < ty) | (y1 > ty + 13) | (x0 < tx) | (x1 > tx + 15);

        // 4 ds_read_b128 (this wave's 16B per corner), swizzled
        uint4 C0 = *(const uint4*)&tile[(P0 << 5) + ((q ^ (P0 & 7)) << 2)];
        uint4 C1 = *(const uint4*)&tile[(P1 << 5) + ((q ^ (P1 & 7)) << 2)];
        uint4 C2 = *(const uint4*)&tile[(P2 << 5) + ((q ^ (P2 & 7)) << 2)];
        uint4 C3 = *(const uint4*)&tile[(P3 << 5) + ((q ^ (P3 & 7)) << 2)];

        // stage kn+1 offsets
        {
            const int knx = min(kn + 1, KNN - 1);
            soy = offp[(size_t)(2 * knx) * HW];
            sox = offp[(size_t)(2 * knx + 1) * HW];
        }

        if (oot) {  // rare: exact global gather fallback
            C0 = *(const uint4*)(xTn + ((((y0 << 7) + x0) << 6) + cbg));
            C1 = *(const uint4*)(xTn + ((((y0 << 7) + x1) << 6) + cbg));
            C2 = *(const uint4*)(xTn + ((((y1 << 7) + x0) << 6) + cbg));
            C3 = *(const uint4*)(xTn + ((((y1 << 7) + x1) << 6) + cbg));
        }

        union { u32 u[4]; bf16x8 v; } B;
        const u32* e0 = (const u32*)&C0;
        const u32* e1 = (const u32*)&C1;
        const u32* e2 = (const u32*)&C2;
        const u32* e3 = (const u32*)&C3;
#pragma unroll
        for (int k = 0; k < 4; k++) {
            float2 a0 = up2v(e0[k]), a1 = up2v(e1[k]);
            float2 a2 = up2v(e2[k]), a3 = up2v(e3[k]);
            float2 h0, h1, s;
            h0.x = fmaf(a1.x, bx, a0.x * ax);
            h0.y = fmaf(a1.y, bx, a0.y * ax);
            h1.x = fmaf(a3.x, bx, a2.x * ax);
            h1.y = fmaf(a3.y, bx, a2.y * ax);
            s.x = fmaf(h1.x, dy, h0.x * cy);
            s.y = fmaf(h1.y, dy, h0.y * cy);
            B.u[k] = pkrn(s);
        }

        const bf16x8* wk = wfl + (((kn << 1) + cc) << 2) * 64;
#pragma unroll
        for (int s4 = 0; s4 < 4; s4++) {
            bf16x8 A = wk[s4 * 64];
            acc[s4] = __builtin_amdgcn_mfma_f32_16x16x32_bf16(A, B.v, acc[s4], 0, 0, 0);
        }
    }

    // ---- cross-wave reduce (cc=1 partials into cc=0) via LDS, then store.
    float* red = (float*)tile;  // 16KB region, conflict-free [s][r][g][lane]
    __syncthreads();            // all tile reads done before aliasing
    if (cc == 1) {
#pragma unroll
        for (int s = 0; s < 4; s++)
#pragma unroll
            for (int r = 0; r < 4; r++)
                red[(((s << 2) + r) << 8) + (g << 6) + l] = acc[s][r];
    }
    __syncthreads();
    if (cc == 0) {
        const int rq = l >> 4;
        float* op = out + ((size_t)(n * OCH) << 14);
#pragma unroll
        for (int s = 0; s < 4; s++) {
            const int ocb = (s << 4) + (rq << 2);
#pragma unroll
            for (int r = 0; r < 4; r++) {
                float v = acc[s][r] + red[(((s << 2) + r) << 8) + (g << 6) + l];
                op[((ocb + r) << 14) + rr] = v;
            }
        }
    }
}

// ---- fallback (ws too small): round-1 style direct kernel
__global__ __launch_bounds__(256) void dcn_fallback_kernel(
    const float* __restrict__ x, const float* __restrict__ off,
    const float* __restrict__ w, float* __restrict__ out) {
    int p = blockIdx.x * blockDim.x + threadIdx.x;
    int n = p / HW, r = p % HW, oh = r / WW, ow = r % WW;
    float acc[OCH];
#pragma unroll
    for (int i = 0; i < OCH; i++) acc[i] = 0.f;
    const float* xn = x + n * (CI * HW);
    const float* offn = off + n * (2 * KNN * HW);
    for (int kn = 0; kn < KNN; kn++) {
        float iy = (float)oh + offn[(2 * kn) * HW + r];
        float ix = (float)ow + offn[(2 * kn + 1) * HW + r];
        float y0f = floorf(iy), x0f = floorf(ix);
        float wy1 = iy - y0f, wy0 = 1.f - wy1, wx1 = ix - x0f, wx0 = 1.f - wx1;
        float my0 = (y0f >= 0.f && y0f <= 127.f) ? 1.f : 0.f;
        float my1 = (y0f >= -1.f && y0f <= 126.f) ? 1.f : 0.f;
        float mx0 = (x0f >= 0.f && x0f <= 127.f) ? 1.f : 0.f;
        float mx1 = (x0f >= -1.f && x0f <= 126.f) ? 1.f : 0.f;
        float w00 = wy0 * wx0 * my0 * mx0, w01 = wy0 * wx1 * my0 * mx1;
        float w10 = wy1 * wx0 * my1 * mx0, w11 = wy1 * wx1 * my1 * mx1;
        int y0 = min(max((int)y0f, 0), 127), y1 = min(max((int)y0f + 1, 0), 127);
        int x0 = min(max((int)x0f, 0), 127), x1 = min(max((int)x0f + 1, 0), 127);
        int o00 = y0 * WW + x0, o01 = y0 * WW + x1, o10 = y1 * WW + x0, o11 = y1 * WW + x1;
        for (int c = 0; c < CI; c++) {
            const float* xc = xn + c * HW;
            float s = xc[o00] * w00 + xc[o01] * w01 + xc[o10] * w10 + xc[o11] * w11;
#pragma unroll
            for (int oc = 0; oc < OCH; oc++) acc[oc] += w[(oc * CI + c) * KNN + kn] * s;
        }
    }
    float* outp = out + n * (OCH * HW) + r;
#pragma unroll
    for (int oc = 0; oc < OCH; oc++) outp[oc * HW] = acc[oc];
}

extern "C" void kernel_launch(void* const* d_in, const int* in_sizes, int n_in,
                              void* d_out, int out_size, void* d_ws, size_t ws_size,
                              hipStream_t stream) {
    const float* x = (const float*)d_in[0];
    const float* off = (const float*)d_in[1];
    const float* w = (const float*)d_in[2];
    float* out = (float*)d_out;

    const size_t xT_elems = (size_t)NB * HW * CI;             // 4,194,304 u16
    const size_t wf_elems = (size_t)KNN * 2 * 4 * 64 * 8;     // 36,864 u16
    const size_t need = (xT_elems + wf_elems) * sizeof(u16);  // ~8.46 MB

    if (ws_size >= need) {
        u16* xT = (u16*)d_ws;
        u16* wfr = xT + xT_elems;
        const int wf_blocks = (int)((wf_elems + 255) / 256);  // 144
        prep_kernel<<<NB * 256 + wf_blocks, 256, 0, stream>>>(x, w, xT, wfr);
        dcn_main_kernel<<<NB * 256, 512, 0, stream>>>(xT, off, wfr, out);
    } else {
        dcn_fallback_kernel<<<(NB * HW) / 256, 256, 0, stream>>>(x, off, w, out);
    }
}